// Round 4
// baseline (804.953 us; speedup 1.0000x reference)
//
#include <hip/hip_runtime.h>
#include <hip/hip_bf16.h>

using bf16 = __hip_bfloat16;
using bf16x8 = __attribute__((ext_vector_type(8))) short;
using f32x4  = __attribute__((ext_vector_type(4))) float;

#define MFMA16(a,b,c) __builtin_amdgcn_mfma_f32_16x16x32_bf16(a,b,c,0,0,0)

static __device__ __forceinline__ unsigned short f2bs(float v){
  bf16 t = __float2bfloat16(v); unsigned short s; __builtin_memcpy(&s,&t,2); return s;
}
static __device__ __forceinline__ float bs2f(unsigned short s){
  bf16 t; __builtin_memcpy(&t,&s,2); return __bfloat162float(t);
}

__global__ void k_zero(float* __restrict__ p, int n){
  int i = blockIdx.x*blockDim.x + threadIdx.x;
  if (i < n) p[i] = 0.f;
}

// ---------------- split fp32 -> bf16 hi (+ optional lo residual) ----------------
__global__ __launch_bounds__(256) void k_split(const float* __restrict__ src,
                                               unsigned short* __restrict__ hi,
                                               unsigned short* __restrict__ lo, int n){
  int i = blockIdx.x*256 + threadIdx.x;
  if (i >= n) return;
  float v = src[i];
  unsigned short h = f2bs(v);
  hi[i] = h;
  if (lo) lo[i] = f2bs(v - bs2f(h));
}

// ---------------- pad (nmat,49,512) fp32 -> (nmat,64,512) split bf16, zero rows 49..63 ----------------
__global__ __launch_bounds__(256) void k_pad(const float* __restrict__ src,
                                             unsigned short* __restrict__ dh,
                                             unsigned short* __restrict__ dl, int nmat){
  long e = ((long)blockIdx.x*256 + threadIdx.x) * 4;
  long total = (long)nmat*64*512;
  if (e >= total) return;
  int rem = (int)(e % (64*512));
  int d = rem >> 9;
  unsigned short h[4], l[4];
  if (d < 49){
    int mat = (int)(e / (64*512));
    int c = rem & 511;
    const float* s = src + ((long)mat*49 + d)*512 + c;
    #pragma unroll
    for (int t=0;t<4;++t){
      float v = s[t];
      h[t] = f2bs(v);
      l[t] = f2bs(v - bs2f(h[t]));
    }
  } else {
    #pragma unroll
    for (int t=0;t<4;++t){ h[t]=0; l[t]=0; }
  }
  uint2 vh, vl; __builtin_memcpy(&vh,h,8); __builtin_memcpy(&vl,l,8);
  *(uint2*)(dh + e) = vh;
  *(uint2*)(dl + e) = vl;
}

// ---------------- C = A @ W^T + bias. Split-bf16 inputs, fp32 acc. ----------------
// TERMS: 3 = Ah*Wh + Al*Wh + Ah*Wl ; 2 = Ah*W + Al*W ; 1 = Ah*Wh.
// BIAS: 0 none, 1 per-col fp32, 2 per-row fp32. SOUT: write split (hi+lo) or single bf16.
template<int TERMS, int BIAS, bool SOUT, int WM, int WN>
__global__ __launch_bounds__(256) void k_gemm(
    const unsigned short* __restrict__ Ah, const unsigned short* __restrict__ Al, long a_bs,
    const unsigned short* __restrict__ Wh, const unsigned short* __restrict__ Wl, long w_bs,
    const float* __restrict__ bias,
    unsigned short* __restrict__ Ch, unsigned short* __restrict__ Cl, long c_bs,
    int K, int N)
{
  const int z = blockIdx.z;
  const unsigned short* Abh = Ah + (long)z*a_bs;
  const unsigned short* Abl = (TERMS>=2) ? Al + (long)z*a_bs : nullptr;
  const unsigned short* Wbh = Wh + (long)z*w_bs;
  const unsigned short* Wbl = (TERMS==3) ? Wl + (long)z*w_bs : nullptr;
  unsigned short* Cbh = Ch + (long)z*c_bs;
  unsigned short* Cbl = SOUT ? Cl + (long)z*c_bs : nullptr;
  int tid = threadIdx.x, wave = tid>>6, lane = tid&63, quad = lane>>4, l15 = lane&15;
  int wm = (WN==1) ? wave : wave / WN;
  int wn = (WN==1) ? 0    : wave % WN;
  int row0 = blockIdx.x*(64*WM) + wm*64;
  int col0 = blockIdx.y*(64*WN) + wn*64;
  f32x4 acc[4][4] = {};
  for (int k0 = 0; k0 < K; k0 += 32) {
    int ka = k0 + quad*8;
    bf16x8 ah[4], al[4], wh[4], wl[4];
    #pragma unroll
    for (int t=0;t<4;++t){
      ah[t] = *(const bf16x8*)(Abh + (long)(row0 + t*16 + l15)*K + ka);
      if (TERMS>=2) al[t] = *(const bf16x8*)(Abl + (long)(row0 + t*16 + l15)*K + ka);
      wh[t] = *(const bf16x8*)(Wbh + (long)(col0 + t*16 + l15)*K + ka);
      if (TERMS==3) wl[t] = *(const bf16x8*)(Wbl + (long)(col0 + t*16 + l15)*K + ka);
    }
    #pragma unroll
    for (int tm=0;tm<4;++tm){
      #pragma unroll
      for (int tn=0;tn<4;++tn){
        acc[tm][tn] = MFMA16(ah[tm], wh[tn], acc[tm][tn]);
        if (TERMS>=2) acc[tm][tn] = MFMA16(al[tm], wh[tn], acc[tm][tn]);
        if (TERMS==3) acc[tm][tn] = MFMA16(ah[tm], wl[tn], acc[tm][tn]);
      }
    }
  }
  #pragma unroll
  for (int tm=0;tm<4;++tm){
    #pragma unroll
    for (int tn=0;tn<4;++tn){
      #pragma unroll
      for (int r=0;r<4;++r){
        int row = row0 + tm*16 + quad*4 + r;
        int col = col0 + tn*16 + l15;
        float v = acc[tm][tn][r];
        if (BIAS==1) v += bias[col];
        else if (BIAS==2) v += bias[row];
        long idx = (long)row*N + col;
        unsigned short h = f2bs(v);
        Cbh[idx] = h;
        if (SOUT) Cbl[idx] = f2bs(v - bs2f(h));
      }
    }
  }
}

// ---------------- stage-1 attention (split precision throughout) ----------------
// q1,k1 split (.,64,256); v1T split (16,512,64) -> fea split (192,64,512)
__global__ __launch_bounds__(256) void k_attn1(
    const unsigned short* __restrict__ qh, const unsigned short* __restrict__ ql,
    const unsigned short* __restrict__ kh, const unsigned short* __restrict__ kl,
    const unsigned short* __restrict__ vh, const unsigned short* __restrict__ vl,
    unsigned short* __restrict__ fh, unsigned short* __restrict__ fl)
{
  __shared__ float Sb[64][72];
  __shared__ __align__(16) unsigned short Ph[64][72];
  __shared__ __align__(16) unsigned short Pl[64][72];
  int bn = blockIdx.x, b = bn/12;
  int tid=threadIdx.x, wave=tid>>6, lane=tid&63, quad=lane>>4, l15=lane&15;
  const unsigned short* Qh = qh + (long)bn*64*256;
  const unsigned short* Ql = ql + (long)bn*64*256;
  const unsigned short* Kh = kh + (long)b *64*256;
  const unsigned short* Kl = kl + (long)b *64*256;
  f32x4 sacc[4] = {};
  for (int k0=0;k0<256;k0+=32){
    int ka = k0 + quad*8;
    bf16x8 qfh = *(const bf16x8*)(Qh + (long)(16*wave + l15)*256 + ka);
    bf16x8 qfl = *(const bf16x8*)(Ql + (long)(16*wave + l15)*256 + ka);
    #pragma unroll
    for (int t=0;t<4;++t){
      bf16x8 kfh = *(const bf16x8*)(Kh + (long)(t*16 + l15)*256 + ka);
      bf16x8 kfl = *(const bf16x8*)(Kl + (long)(t*16 + l15)*256 + ka);
      sacc[t] = MFMA16(qfh, kfh, sacc[t]);
      sacc[t] = MFMA16(qfl, kfh, sacc[t]);
      sacc[t] = MFMA16(qfh, kfl, sacc[t]);
    }
  }
  #pragma unroll
  for (int t=0;t<4;++t)
    #pragma unroll
    for (int r=0;r<4;++r)
      Sb[16*wave + quad*4 + r][t*16 + l15] = sacc[t][r] * 0.0625f;
  __syncthreads();
  if (tid < 64){
    float m = -1e30f;
    for (int c=0;c<49;++c) m = fmaxf(m, Sb[tid][c]);
    float s = 0.f;
    for (int c=0;c<49;++c){ float e = __expf(Sb[tid][c]-m); s += e; Sb[tid][c]=e; }
    float inv = 1.f/s;
    for (int c=0;c<64;++c){
      float p = (c<49) ? Sb[tid][c]*inv : 0.f;
      unsigned short h = f2bs(p);
      Ph[tid][c] = h;
      Pl[tid][c] = f2bs(p - bs2f(h));
    }
  }
  __syncthreads();
  const unsigned short* Vh = vh + (long)b*512*64;
  const unsigned short* Vl = vl + (long)b*512*64;
  unsigned short* Fh = fh + (long)bn*64*512;
  unsigned short* Fl = fl + (long)bn*64*512;
  for (int nc=0;nc<4;++nc){
    f32x4 acc[8] = {};
    #pragma unroll
    for (int kk=0;kk<2;++kk){
      int k0 = kk*32 + quad*8;
      bf16x8 pfh = *(const bf16x8*)(&Ph[16*wave + l15][k0]);
      bf16x8 pfl = *(const bf16x8*)(&Pl[16*wave + l15][k0]);
      #pragma unroll
      for (int t=0;t<8;++t){
        bf16x8 vfh = *(const bf16x8*)(Vh + (long)(nc*128 + t*16 + l15)*64 + k0);
        bf16x8 vfl = *(const bf16x8*)(Vl + (long)(nc*128 + t*16 + l15)*64 + k0);
        acc[t] = MFMA16(pfh, vfh, acc[t]);
        acc[t] = MFMA16(pfl, vfh, acc[t]);
        acc[t] = MFMA16(pfh, vfl, acc[t]);
      }
    }
    #pragma unroll
    for (int t=0;t<8;++t){
      #pragma unroll
      for (int r=0;r<4;++r){
        long idx = (long)(16*wave + quad*4 + r)*512 + nc*128 + t*16 + l15;
        float v = acc[t][r];
        unsigned short h = f2bs(v);
        Fh[idx] = h;
        Fl[idx] = f2bs(v - bs2f(h));
      }
    }
  }
}

// ---------------- stage-2 logits + softmax -> P2 (single bf16) ----------------
__global__ __launch_bounds__(256) void k_attnA(
    const unsigned short* __restrict__ qh, const unsigned short* __restrict__ ql,
    const unsigned short* __restrict__ kh, const unsigned short* __restrict__ kl,
    unsigned short* __restrict__ P2)
{
  __shared__ float Sb[64][72];
  int p = blockIdx.x, b = blockIdx.y;
  int i = p/12, j = p%12;
  int tid=threadIdx.x, wave=tid>>6, lane=tid&63, quad=lane>>4, l15=lane&15;
  const unsigned short* Qh = qh + ((long)(b*12 + j))*64*256;
  const unsigned short* Ql = ql + ((long)(b*12 + j))*64*256;
  const unsigned short* Kh = kh + ((long)(b*12 + i))*64*256;
  const unsigned short* Kl = kl + ((long)(b*12 + i))*64*256;
  f32x4 sacc[4] = {};
  for (int k0=0;k0<256;k0+=32){
    int ka = k0 + quad*8;
    bf16x8 qfh = *(const bf16x8*)(Qh + (long)(16*wave + l15)*256 + ka);
    bf16x8 qfl = *(const bf16x8*)(Ql + (long)(16*wave + l15)*256 + ka);
    #pragma unroll
    for (int t=0;t<4;++t){
      bf16x8 kfh = *(const bf16x8*)(Kh + (long)(t*16 + l15)*256 + ka);
      bf16x8 kfl = *(const bf16x8*)(Kl + (long)(t*16 + l15)*256 + ka);
      sacc[t] = MFMA16(qfh, kfh, sacc[t]);
      sacc[t] = MFMA16(qfl, kfh, sacc[t]);
      sacc[t] = MFMA16(qfh, kfl, sacc[t]);
    }
  }
  #pragma unroll
  for (int t=0;t<4;++t)
    #pragma unroll
    for (int r=0;r<4;++r)
      Sb[16*wave + quad*4 + r][t*16 + l15] = sacc[t][r] * 0.0625f;
  __syncthreads();
  if (tid < 64){
    float m = -1e30f;
    for (int c=0;c<49;++c) m = fmaxf(m, Sb[tid][c]);
    float s = 0.f;
    for (int c=0;c<49;++c){ float e = __expf(Sb[tid][c]-m); s += e; Sb[tid][c]=e; }
    float inv = 1.f/s;
    unsigned short* row = P2 + ((long)(b*144 + p)*64 + tid)*64;
    for (int c=0;c<64;++c)
      row[c] = f2bs((c<49) ? Sb[tid][c]*inv : 0.f);
  }
}

// ---------------- stage-2 PV (edge-projected) -> fp32 out + BN stats ----------------
__global__ __launch_bounds__(256) void k_attnB(
    const unsigned short* __restrict__ P2, const unsigned short* __restrict__ EV,
    float* __restrict__ out, float* __restrict__ stats)
{
  __shared__ float red[8];
  int p = blockIdx.x, b = blockIdx.y;
  int i = p/12;
  int tid=threadIdx.x, wave=tid>>6, lane=tid&63, quad=lane>>4, l15=lane&15;
  const unsigned short* Pz = P2 + (long)(b*144 + p)*64*64;
  const unsigned short* E  = EV + ((long)(b*12 + i))*512*64;
  float psum = 0.f, psq = 0.f;
  for (int nc=0;nc<4;++nc){
    f32x4 acc[8] = {};
    #pragma unroll
    for (int kk=0;kk<2;++kk){
      int k0 = kk*32 + quad*8;
      bf16x8 pf = *(const bf16x8*)(Pz + (long)(16*wave + l15)*64 + k0);
      #pragma unroll
      for (int t=0;t<8;++t){
        bf16x8 ef = *(const bf16x8*)(E + (long)(nc*128 + t*16 + l15)*64 + k0);
        acc[t] = MFMA16(pf, ef, acc[t]);
      }
    }
    #pragma unroll
    for (int t=0;t<8;++t){
      #pragma unroll
      for (int r=0;r<4;++r){
        int q = 16*wave + quad*4 + r;
        if (q < 49){
          float v = acc[t][r];
          psum += v; psq += v*v;
          out[(((long)(b*144 + p))*49 + q)*512 + (nc*128 + t*16 + l15)] = v;
        }
      }
    }
  }
  #pragma unroll
  for (int off=32; off; off>>=1){
    psum += __shfl_xor(psum, off, 64);
    psq  += __shfl_xor(psq , off, 64);
  }
  if (lane==0){ red[wave]=psum; red[4+wave]=psq; }
  __syncthreads();
  if (tid==0){
    atomicAdd(&stats[p],     red[0]+red[1]+red[2]+red[3]);
    atomicAdd(&stats[144+p], red[4]+red[5]+red[6]+red[7]);
  }
}

// ---------------- BatchNorm normalize in-place (fp32) ----------------
__global__ __launch_bounds__(256) void k_bn(float* __restrict__ out, const float* __restrict__ stats,
                                            const float* __restrict__ bnw, const float* __restrict__ bnb)
{
  long e = ((long)blockIdx.x*256 + threadIdx.x)*4;
  int p = (int)((e / 25088) % 144);
  const float invc = 1.f/401408.f;
  float mean = stats[p] * invc;
  float var  = stats[144+p] * invc - mean*mean;
  float inv  = rsqrtf(var + 1e-5f);
  float g  = bnw[p] * inv;
  float sh = bnb[p] - mean*g;
  float4 v = *(float4*)(out + e);
  v.x = v.x*g + sh; v.y = v.y*g + sh; v.z = v.z*g + sh; v.w = v.w*g + sh;
  *(float4*)(out + e) = v;
}

extern "C" void kernel_launch(void* const* d_in, const int* in_sizes, int n_in,
                              void* d_out, int out_size, void* d_ws, size_t ws_size,
                              hipStream_t stream)
{
  const float* cf  = (const float*)d_in[0];
  const float* gf  = (const float*)d_in[1];
  const float* fqw = (const float*)d_in[2];   const float* fqb = (const float*)d_in[3];
  const float* fkw = (const float*)d_in[4];   const float* fkb = (const float*)d_in[5];
  const float* fvw = (const float*)d_in[6];   const float* fvb = (const float*)d_in[7];
  const float* aqw = (const float*)d_in[8];   const float* aqb = (const float*)d_in[9];
  const float* akw = (const float*)d_in[10];  const float* akb = (const float*)d_in[11];
  const float* avw = (const float*)d_in[12];  const float* avb = (const float*)d_in[13];
  const float* ew  = (const float*)d_in[14];  const float* ebv = (const float*)d_in[15];
  const float* bnw = (const float*)d_in[16];  const float* bnb = (const float*)d_in[17];

  // ---- d_ws (~31.5 MB): stats | P2 (weights overlaid; dead before P2 written) | EV ----
  char* WS = (char*)d_ws;
  float* stats = (float*)WS;                                   // 288 fp32
  unsigned short* P2 = (unsigned short*)(WS + 4096);           // 16*144*64*64
  unsigned short* EV = (unsigned short*)(WS + 4096 + 18874368);// 192*512*64
  unsigned short* wp = P2;  // weights overlay (consumed before attnA writes P2)
  unsigned short* w_fqw_h = wp; wp += 131072;  unsigned short* w_fqw_l = wp; wp += 131072;
  unsigned short* w_fkw_h = wp; wp += 131072;  unsigned short* w_fkw_l = wp; wp += 131072;
  unsigned short* w_fvw_h = wp; wp += 262144;  unsigned short* w_fvw_l = wp; wp += 262144;
  unsigned short* w_aqw_h = wp; wp += 131072;  unsigned short* w_aqw_l = wp; wp += 131072;
  unsigned short* w_akw_h = wp; wp += 131072;  unsigned short* w_akw_l = wp; wp += 131072;
  unsigned short* w_avw_h = wp; wp += 262144;
  unsigned short* w_ew_h  = wp; wp += 262144;

  // ---- d_out (231 MB fp32) as bf16 scratch for intermediates dead before k_attnB ----
  unsigned short* S = (unsigned short*)d_out;
  unsigned short* cfh = S; S += 6291456;  unsigned short* cfl = S; S += 6291456;
  unsigned short* gfh = S; S += 524288;   unsigned short* gfl = S; S += 524288;
  unsigned short* q1h = S; S += 3145728;  unsigned short* q1l = S; S += 3145728;
  unsigned short* k1h = S; S += 262144;   unsigned short* k1l = S; S += 262144;
  unsigned short* v1h = S; S += 524288;   unsigned short* v1l = S; S += 524288;
  unsigned short* feh = S; S += 6291456;  unsigned short* fel = S; S += 6291456;
  unsigned short* q2h = S; S += 3145728;  unsigned short* q2l = S; S += 3145728;
  unsigned short* k2h = S; S += 3145728;  unsigned short* k2l = S; S += 3145728;
  unsigned short* v2  = S; S += 6291456;  // single bf16

  k_zero<<<1, 320, 0, stream>>>(stats, 288);

  k_split<<<512, 256, 0, stream>>>(fqw, w_fqw_h, w_fqw_l, 131072);
  k_split<<<512, 256, 0, stream>>>(fkw, w_fkw_h, w_fkw_l, 131072);
  k_split<<<1024,256, 0, stream>>>(fvw, w_fvw_h, w_fvw_l, 262144);
  k_split<<<512, 256, 0, stream>>>(aqw, w_aqw_h, w_aqw_l, 131072);
  k_split<<<512, 256, 0, stream>>>(akw, w_akw_h, w_akw_l, 131072);
  k_split<<<1024,256, 0, stream>>>(avw, w_avw_h, nullptr, 262144);
  k_split<<<1024,256, 0, stream>>>(ew,  w_ew_h,  nullptr, 262144);

  k_pad<<<6144, 256, 0, stream>>>(cf, cfh, cfl, 192);
  k_pad<<<512,  256, 0, stream>>>(gf, gfh, gfl, 16);

  // q1 = cfp @ fqw^T + fqb   (12288,256) split out
  k_gemm<3,1,true,1,4><<<dim3(192,1,1),256,0,stream>>>(cfh,cfl,0, w_fqw_h,w_fqw_l,0, fqb, q1h,q1l,0, 512,256);
  // k1 = gfp @ fkw^T + fkb   (1024,256)
  k_gemm<3,1,true,1,4><<<dim3(16,1,1),256,0,stream>>>(gfh,gfl,0, w_fkw_h,w_fkw_l,0, fkb, k1h,k1l,0, 512,256);
  // v1T[b] = fvw @ gfp[b]^T + fvb(row)   (16 x 512,64)
  k_gemm<3,2,true,4,1><<<dim3(2,1,16),256,0,stream>>>(w_fvw_h,w_fvw_l,0, gfh,gfl,(long)64*512, fvb, v1h,v1l,(long)512*64, 512,64);

  k_attn1<<<192,256,0,stream>>>(q1h,q1l,k1h,k1l,v1h,v1l,feh,fel);

  // Q2/K2 = fea @ a{q,k}w^T + b  (12288,256) split out
  k_gemm<3,1,true,1,4><<<dim3(192,1,1),256,0,stream>>>(feh,fel,0, w_aqw_h,w_aqw_l,0, aqb, q2h,q2l,0, 512,256);
  k_gemm<3,1,true,1,4><<<dim3(192,1,1),256,0,stream>>>(feh,fel,0, w_akw_h,w_akw_l,0, akb, k2h,k2l,0, 512,256);
  // V2 = fea @ avw^T + avb  (12288,512) single out, 2-term
  k_gemm<2,1,false,1,4><<<dim3(192,2,1),256,0,stream>>>(feh,fel,0, w_avw_h,nullptr,0, avb, v2,nullptr,0, 512,512);
  // EV[bn] = ew @ V2[bn]^T + edge_b(row)  (192 x 512,64) single
  k_gemm<1,2,false,4,1><<<dim3(2,1,192),256,0,stream>>>(w_ew_h,nullptr,0, v2,nullptr,(long)64*512, ebv, EV,nullptr,(long)512*64, 512,64);

  k_attnA<<<dim3(144,16),256,0,stream>>>(q2h,q2l,k2h,k2l,P2);
  k_attnB<<<dim3(144,16),256,0,stream>>>(P2,EV,(float*)d_out,stats);
  k_bn<<<56448,256,0,stream>>>((float*)d_out,stats,bnw,bnb);
}